// Round 10
// baseline (146.221 us; speedup 1.0000x reference)
//
#include <hip/hip_runtime.h>
#include <math.h>

#define DIM 4096
#define NH 32
#define NKV 8
#define HD 128
#define NREP 4
#define ABLK 512   // positions per score block
#define BBLK 256   // positions per pv block (4 waves, 64 t/wave)

#define LD4(p) (*(const float4*)(p))

// ---------------------------------------------------------------------------
// Kernel 1: q/k/v GEMV + fused RoPE (unchanged).
// ---------------------------------------------------------------------------
__global__ __launch_bounds__(256) void qkv_rope_kernel(
    const float* __restrict__ x, const float* __restrict__ fc,
    const float* __restrict__ fs, const float* __restrict__ wq,
    const float* __restrict__ wk, const float* __restrict__ wv,
    float* __restrict__ q_rope, float* __restrict__ k_new,
    float* __restrict__ v_new) {
  int wave = blockIdx.x * 4 + (threadIdx.x >> 6);
  int lane = threadIdx.x & 63;
  const float* W;
  float* dst;
  int r0;
  bool rope;
  if (wave < 2048) {
    W = wq; dst = q_rope; r0 = wave * 2; rope = true;
  } else if (wave < 2560) {
    W = wk; dst = k_new; r0 = (wave - 2048) * 2; rope = true;
  } else {
    W = wv; dst = v_new; r0 = (wave - 2560) * 2; rope = false;
  }
  const float4* x4 = (const float4*)x;
  const float4* w0 = (const float4*)(W + (size_t)r0 * DIM);
  const float4* w1 = (const float4*)(W + (size_t)(r0 + 1) * DIM);
  float a0 = 0.f, a1 = 0.f;
#pragma unroll 4
  for (int c = lane; c < DIM / 4; c += 64) {
    float4 xv = x4[c];
    float4 u = w0[c];
    float4 v = w1[c];
    a0 += xv.x * u.x + xv.y * u.y + xv.z * u.z + xv.w * u.w;
    a1 += xv.x * v.x + xv.y * v.y + xv.z * v.z + xv.w * v.w;
  }
  for (int off = 32; off > 0; off >>= 1) {
    a0 += __shfl_down(a0, off, 64);
    a1 += __shfl_down(a1, off, 64);
  }
  if (lane == 0) {
    if (rope) {
      int jj = (r0 & (HD - 1)) >> 1;
      float c = fc[jj], s = fs[jj];
      dst[r0]     = a0 * c - a1 * s;
      dst[r0 + 1] = a0 * s + a1 * c;
    } else {
      dst[r0]     = a0;
      dst[r0 + 1] = a1;
    }
  }
}

// ---------------------------------------------------------------------------
// Kernel A: scores + exp, line-efficient. Lane = (row r=l>>4, head
// h=(l>>2)&3, chunk c=l&3). Thread dots K bytes {c*16 + j*64 : j=0..7} of
// row t against q (32 regs). The 16 lanes of a row cover every 64B line
// fully (4 h-copies dedup'd by the coalescer) -> 100% line utilization.
// 2 shuffles + 1 exp per row finish (m=0 reference, validated R4-R9).
// ---------------------------------------------------------------------------
__global__ __launch_bounds__(512, 4) void score_kernel(
    const float* __restrict__ q_rope, const float* __restrict__ k_cache,
    float* __restrict__ p_buf, float* __restrict__ partial_l,
    int start_pos, int nsplit_a, int Tpad) {
  int g = blockIdx.x & 7;
  int blk = blockIdx.x >> 3;
  int tid = threadIdx.x;
  int w = tid >> 6, l = tid & 63;
  int r = l >> 4, h = (l >> 2) & 3, c = l & 3;

  // q in registers: head h, float offsets c*4 + j*16
  float4 qreg[8];
  const float* qb = q_rope + (size_t)(g * NREP + h) * HD + c * 4;
#pragma unroll
  for (int j = 0; j < 8; ++j) qreg[j] = LD4(qb + j * 16);

  const float scale = 0.08838834764831845f;  // 1/sqrt(128)
  float lsum = 0.f;

#pragma unroll 2
  for (int i = 0; i < 16; ++i) {
    int t = blk * ABLK + i * 32 + w * 4 + r;
    bool valid = t < start_pos;
    int tc = valid ? t : 0;
    const float* kr = k_cache + ((size_t)tc * NKV + g) * HD + c * 4;
    float s = 0.f;
#pragma unroll
    for (int j = 0; j < 8; ++j) {
      float4 K4 = LD4(kr + j * 16);
      s += K4.x * qreg[j].x + K4.y * qreg[j].y + K4.z * qreg[j].z +
           K4.w * qreg[j].w;
    }
    s += __shfl_xor(s, 1, 64);
    s += __shfl_xor(s, 2, 64);
    float p = valid ? __expf(s * scale) : 0.f;
    if (c == 0) {
      p_buf[((size_t)g * Tpad + t) * 4 + h] = p;
      lsum += p;
    }
  }

  // lsum: sum over r (only c==0 lanes carry data; others hold 0)
  lsum += __shfl_xor(lsum, 16, 64);
  lsum += __shfl_xor(lsum, 32, 64);
  __shared__ float sl[8][4];
  if (l < 16 && c == 0) sl[w][l >> 2] = lsum;  // l == h*4
  __syncthreads();
  if (tid < NREP) {
    float L = 0.f;
#pragma unroll
    for (int ww = 0; ww < 8; ++ww) L += sl[ww][tid];
    partial_l[(g * NREP + tid) * nsplit_a + blk] = L;
  }
}

// ---------------------------------------------------------------------------
// Kernel B: PV. Lane = (head h=l>>4, d-slot ds=l&15). Per t: 2 coalesced
// V float4 loads (dedup'd across the 4 head groups) + 1 broadcast p scalar
// + 16 FMA into registers. No cross-lane ops in the loop.
// ---------------------------------------------------------------------------
__global__ __launch_bounds__(256, 4) void pv_kernel(
    const float* __restrict__ p_buf, const float* __restrict__ v_cache,
    float* __restrict__ partial_o, int start_pos, int nsplit_b, int Tpad) {
  int g = blockIdx.x & 7;
  int split = blockIdx.x >> 3;
  int tid = threadIdx.x;
  int w = tid >> 6, l = tid & 63;
  int h = l >> 4, ds = l & 15;
  int tb = split * BBLK + w * 64;
  const float* pb = p_buf + ((size_t)g * Tpad + tb) * 4 + h;
  float out[8] = {0.f, 0.f, 0.f, 0.f, 0.f, 0.f, 0.f, 0.f};
#pragma unroll 4
  for (int i = 0; i < 64; ++i) {
    int t = tb + i;
    int tcl = t < start_pos ? t : start_pos - 1;  // safe addr; p=0 if invalid
    float p = pb[i * 4];
    const float* vr = v_cache + ((size_t)tcl * NKV + g) * HD + ds * 8;
    float4 Va = LD4(vr);
    float4 Vb = LD4(vr + 4);
    out[0] += p * Va.x; out[1] += p * Va.y;
    out[2] += p * Va.z; out[3] += p * Va.w;
    out[4] += p * Vb.x; out[5] += p * Vb.y;
    out[6] += p * Vb.z; out[7] += p * Vb.w;
  }
  __shared__ float sacc[4][NREP][HD];
  float4 oa, ob;
  oa.x = out[0]; oa.y = out[1]; oa.z = out[2]; oa.w = out[3];
  ob.x = out[4]; ob.y = out[5]; ob.z = out[6]; ob.w = out[7];
  *(float4*)&sacc[w][h][ds * 8] = oa;
  *(float4*)&sacc[w][h][ds * 8 + 4] = ob;
  __syncthreads();
  for (int idx = tid; idx < NREP * HD; idx += 256) {
    int hh = idx >> 7, d = idx & (HD - 1);
    float s = sacc[0][hh][d] + sacc[1][hh][d] + sacc[2][hh][d] +
              sacc[3][hh][d];
    partial_o[((size_t)(g * NREP + hh) * nsplit_b + split) * HD + d] = s;
  }
}

// ---------------------------------------------------------------------------
// Kernel 3: combine splits + new-token contribution (m=0 everywhere).
// ---------------------------------------------------------------------------
__global__ __launch_bounds__(128) void combine_kernel(
    const float* __restrict__ q_rope, const float* __restrict__ k_new,
    const float* __restrict__ v_new, const float* __restrict__ partial_l,
    const float* __restrict__ partial_o, float* __restrict__ attn_out,
    int nsplit_a, int nsplit_b) {
  int hh = blockIdx.x;
  int g = hh >> 2;
  int tid = threadIdx.x;
  __shared__ float sp[128];
  sp[tid] = q_rope[hh * HD + tid] * k_new[g * HD + tid];
  __syncthreads();
  for (int s = 64; s > 0; s >>= 1) {
    if (tid < s) sp[tid] += sp[tid + s];
    __syncthreads();
  }
  float e_new = __expf(sp[0] * 0.08838834764831845f);
  float L = e_new;
  for (int s = 0; s < nsplit_a; ++s) L += partial_l[hh * nsplit_a + s];
  float acc = e_new * v_new[g * HD + tid];
#pragma unroll 4
  for (int s = 0; s < nsplit_b; ++s)
    acc += partial_o[((size_t)hh * nsplit_b + s) * HD + tid];
  attn_out[hh * HD + tid] = acc / L;
}

// ---------------------------------------------------------------------------
// Kernel 4: out = attn @ wo.T (unchanged).
// ---------------------------------------------------------------------------
__global__ __launch_bounds__(256) void out_gemv_kernel(
    const float* __restrict__ attn, const float* __restrict__ wo,
    float* __restrict__ out) {
  int row = blockIdx.x * 4 + (threadIdx.x >> 6);
  int lane = threadIdx.x & 63;
  const float4* a4 = (const float4*)attn;
  const float4* w4 = (const float4*)(wo + (size_t)row * DIM);
  float a = 0.f;
#pragma unroll 4
  for (int c = lane; c < DIM / 4; c += 64) {
    float4 av = a4[c];
    float4 wv = w4[c];
    a += av.x * wv.x + av.y * wv.y + av.z * wv.z + av.w * wv.w;
  }
  for (int off = 32; off > 0; off >>= 1) a += __shfl_down(a, off, 64);
  if (lane == 0) out[row] = a;
}

extern "C" void kernel_launch(void* const* d_in, const int* in_sizes, int n_in,
                              void* d_out, int out_size, void* d_ws,
                              size_t ws_size, hipStream_t stream) {
  const float* x       = (const float*)d_in[0];
  const float* fc      = (const float*)d_in[1];
  const float* fs      = (const float*)d_in[2];
  const float* k_cache = (const float*)d_in[3];
  const float* v_cache = (const float*)d_in[4];
  const float* wq      = (const float*)d_in[5];
  const float* wk      = (const float*)d_in[6];
  const float* wv      = (const float*)d_in[7];
  const float* wo      = (const float*)d_in[8];
  float* out = (float*)d_out;

  int start_pos = in_sizes[3] / (NKV * HD);  // cache length (32767)
  int nsplit_a = (start_pos + ABLK - 1) / ABLK;   // 64
  int Tpad = nsplit_a * ABLK;                     // 32768
  int nsplit_b = Tpad / BBLK;                     // 128

  float* ws = (float*)d_ws;
  float* q_rope    = ws;                               // 4096
  float* k_new     = ws + 4096;                        // 1024
  float* v_new     = ws + 5120;                        // 1024
  float* attn_out  = ws + 6144;                        // 4096
  float* partial_l = ws + 10240;                       // NH*nsplit_a
  float* partial_o = partial_l + NH * nsplit_a;        // NH*nsplit_b*HD
  float* p_buf     = partial_o + (size_t)NH * nsplit_b * HD;  // 8*Tpad*4

  qkv_rope_kernel<<<768, 256, 0, stream>>>(x, fc, fs, wq, wk, wv, q_rope,
                                           k_new, v_new);
  score_kernel<<<8 * nsplit_a, 512, 0, stream>>>(
      q_rope, k_cache, p_buf, partial_l, start_pos, nsplit_a, Tpad);
  pv_kernel<<<8 * nsplit_b, BBLK, 0, stream>>>(
      p_buf, v_cache, partial_o, start_pos, nsplit_b, Tpad);
  combine_kernel<<<NH, 128, 0, stream>>>(q_rope, k_new, v_new, partial_l,
                                         partial_o, attn_out, nsplit_a,
                                         nsplit_b);
  out_gemv_kernel<<<1024, 256, 0, stream>>>(attn_out, wo, out);
}

// Round 15
// 92.828 us; speedup vs baseline: 1.5752x; 1.5752x over previous
//
#include <hip/hip_runtime.h>
#include <math.h>

// R15 == R13/R14 source (nt-load A/B on the R4 vehicle); prior two rounds
// died to UnresponsiveContainer before launch.

#define DIM 4096
#define NH 32
#define NKV 8
#define HD 128
#define NREP 4
#define RSPLIT 128

typedef float f32x4 __attribute__((ext_vector_type(4)));

// ---------------------------------------------------------------------------
// Kernel 1: q/k/v GEMV + fused RoPE.
// ---------------------------------------------------------------------------
__global__ __launch_bounds__(256) void qkv_rope_kernel(
    const float* __restrict__ x, const float* __restrict__ fc,
    const float* __restrict__ fs, const float* __restrict__ wq,
    const float* __restrict__ wk, const float* __restrict__ wv,
    float* __restrict__ q_rope, float* __restrict__ k_new,
    float* __restrict__ v_new) {
  int wave = blockIdx.x * 4 + (threadIdx.x >> 6);
  int lane = threadIdx.x & 63;
  const float* W;
  float* dst;
  int r0;
  bool rope;
  if (wave < 2048) {            // q: 4096 rows
    W = wq; dst = q_rope; r0 = wave * 2; rope = true;
  } else if (wave < 2560) {     // k: 1024 rows
    W = wk; dst = k_new; r0 = (wave - 2048) * 2; rope = true;
  } else {                      // v: 1024 rows
    W = wv; dst = v_new; r0 = (wave - 2560) * 2; rope = false;
  }
  const float4* x4 = (const float4*)x;
  const float4* w0 = (const float4*)(W + (size_t)r0 * DIM);
  const float4* w1 = (const float4*)(W + (size_t)(r0 + 1) * DIM);
  float a0 = 0.f, a1 = 0.f;
#pragma unroll 4
  for (int c = lane; c < DIM / 4; c += 64) {
    float4 xv = x4[c];
    float4 u = w0[c];
    float4 v = w1[c];
    a0 += xv.x * u.x + xv.y * u.y + xv.z * u.z + xv.w * u.w;
    a1 += xv.x * v.x + xv.y * v.y + xv.z * v.z + xv.w * v.w;
  }
  for (int off = 32; off > 0; off >>= 1) {
    a0 += __shfl_down(a0, off, 64);
    a1 += __shfl_down(a1, off, 64);
  }
  if (lane == 0) {
    if (rope) {
      int j = (r0 & (HD - 1)) >> 1;
      float c = fc[j], s = fs[j];
      dst[r0]     = a0 * c - a1 * s;
      dst[r0 + 1] = a0 * s + a1 * c;
    } else {
      dst[r0]     = a0;
      dst[r0 + 1] = a1;
    }
  }
}

#define LD4(p) (*(const float4*)(p))
// non-temporal load: bypass LLC allocation for the streaming K/V cache.
// Must use a native clang ext_vector type (HIP_vector_type rejected).
#define NT4(p) (__builtin_nontemporal_load((const f32x4*)(p)))

#define DOT4(sv, h)                                                         \
  sv = A.x * qf[h][0] + A.y * qf[h][1] + A.z * qf[h][2] + A.w * qf[h][3] +  \
       B.x * qf[h][4] + B.y * qf[h][5] + B.z * qf[h][6] + B.w * qf[h][7];

#define PV8(h, e)                                                           \
  acc[h][0] += (e)*VA.x; acc[h][1] += (e)*VA.y;                             \
  acc[h][2] += (e)*VA.z; acc[h][3] += (e)*VA.w;                             \
  acc[h][4] += (e)*VB.x; acc[h][5] += (e)*VB.y;                             \
  acc[h][6] += (e)*VB.z; acc[h][7] += (e)*VB.w;

// One position-step: K-dots for 4 heads, 5-shuffle transposed reduce,
// 3-shuffle broadcast, exp (fixed m=0 reference), PV accumulate.
#define STEP(KA_, KB_, VA_, VB_, VALID)                                     \
  {                                                                         \
    auto A = KA_; auto B = KB_;                                             \
    float s0, s1, s2, s3;                                                   \
    DOT4(s0, 0); DOT4(s1, 1); DOT4(s2, 2); DOT4(s3, 3);                     \
    float pp = hi8 ? s2 : s0, pq = hi8 ? s0 : s2;                           \
    pp += __shfl_xor(pq, 8, 64);                                            \
    float rr = hi8 ? s3 : s1, rs = hi8 ? s1 : s3;                           \
    rr += __shfl_xor(rs, 8, 64);                                            \
    float u = hi4 ? rr : pp, uvx = hi4 ? pp : rr;                           \
    u += __shfl_xor(uvx, 4, 64);                                            \
    u += __shfl_xor(u, 1, 64);                                              \
    u += __shfl_xor(u, 2, 64);                                              \
    float u4 = __shfl_xor(u, 4, 64);                                        \
    float u8 = __shfl_xor(u, 8, 64);                                        \
    float u12 = __shfl_xor(u4, 8, 64);                                      \
    float q0 = hi4 ? u4 : u,   q1 = hi4 ? u : u4;                           \
    float q2 = hi4 ? u12 : u8, q3 = hi4 ? u8 : u12;                         \
    float w0 = hi8 ? q2 : q0, w1 = hi8 ? q3 : q1;                           \
    float w2 = hi8 ? q0 : q2, w3 = hi8 ? q1 : q3;                           \
    float e0 = __expf((VALID) ? w0 * scale : -1e30f);                       \
    float e1 = __expf((VALID) ? w1 * scale : -1e30f);                       \
    float e2 = __expf((VALID) ? w2 * scale : -1e30f);                       \
    float e3 = __expf((VALID) ? w3 * scale : -1e30f);                       \
    lsum[0] += e0; lsum[1] += e1; lsum[2] += e2; lsum[3] += e3;             \
    auto VA = VA_; auto VB = VB_;                                           \
    PV8(0, e0) PV8(1, e1) PV8(2, e2) PV8(3, e3)                             \
  }

// ---------------------------------------------------------------------------
// Kernel 2: flash-decode partials, single online pass (m=0 reference —
// validated R4-R10). Identical to the R4 structure (best vehicle, 96.5us)
// EXCEPT: all K/V loads are non-temporal to bypass LLC allocation.
// ---------------------------------------------------------------------------
__global__ __launch_bounds__(256, 4) void attn_partial_kernel(
    const float* __restrict__ q_rope, const float* __restrict__ k_cache,
    const float* __restrict__ v_cache, const float* __restrict__ k_new,
    const float* __restrict__ v_new, float* __restrict__ partial_m,
    float* __restrict__ partial_l, float* __restrict__ partial_o,
    int start_pos, int T, int CH) {
  int g = blockIdx.x % NKV;
  int split = blockIdx.x / NKV;
  int t0 = split * CH;
  int tid = threadIdx.x;
  int wvi = tid >> 6;
  int lane = tid & 63;
  int grp = lane >> 4;
  int lig = lane & 15;
  int tl0 = wvi * 4 + grp;
  int dbase = lig * 8;
  bool hi8 = (lig & 8) != 0, hi4 = (lig & 4) != 0;

  __shared__ float s_wacc[4][4][HD];
  __shared__ float s_wl[4][4];

  float qf[4][8];
#pragma unroll
  for (int h = 0; h < 4; ++h)
#pragma unroll
    for (int e = 0; e < 8; ++e)
      qf[h][e] = q_rope[(g * NREP + h) * HD + dbase + e];

  float lsum[4] = {0.f, 0.f, 0.f, 0.f};
  float acc[4][8];
#pragma unroll
  for (int h = 0; h < 4; ++h)
#pragma unroll
    for (int e = 0; e < 8; ++e) acc[h][e] = 0.f;

  const float scale = 0.08838834764831845f;  // 1/sqrt(128)
  int iters = CH >> 4;
  bool full = (t0 + CH + 16 <= start_pos);   // margin for 1-stage prefetch
  const size_t kstep = (size_t)16 * NKV * HD;

  if (full) {
    const float* kp = k_cache + ((size_t)(t0 + tl0) * NKV + g) * HD + dbase;
    const float* vp = v_cache + ((size_t)(t0 + tl0) * NKV + g) * HD + dbase;
    f32x4 KA0 = NT4(kp), KB0 = NT4(kp + 4);
    f32x4 VA0 = NT4(vp), VB0 = NT4(vp + 4);
    kp += kstep; vp += kstep;
    for (int i = 0; i < iters; i += 2) {
      f32x4 KA1 = NT4(kp), KB1 = NT4(kp + 4);
      f32x4 VA1 = NT4(vp), VB1 = NT4(vp + 4);
      kp += kstep; vp += kstep;
      __builtin_amdgcn_sched_barrier(0);   // loads above stay above
      STEP(KA0, KB0, VA0, VB0, true);
      KA0 = NT4(kp); KB0 = NT4(kp + 4);
      VA0 = NT4(vp); VB0 = NT4(vp + 4);
      kp += kstep; vp += kstep;
      __builtin_amdgcn_sched_barrier(0);
      STEP(KA1, KB1, VA1, VB1, true);
    }
  } else {
    for (int i = 0; i < iters; ++i) {
      int t = t0 + i * 16 + tl0;
      bool valid = (t < T);
      const float* kp;
      const float* vp;
      if (t < start_pos) {
        kp = k_cache + ((size_t)t * NKV + g) * HD;
        vp = v_cache + ((size_t)t * NKV + g) * HD;
      } else {
        kp = k_new + (size_t)g * HD;   // also safe addr for invalid t
        vp = v_new + (size_t)g * HD;
      }
      f32x4 KA = NT4(kp + dbase), KB = NT4(kp + dbase + 4);
      f32x4 VAx = NT4(vp + dbase), VBx = NT4(vp + dbase + 4);
      STEP(KA, KB, VAx, VBx, valid);
    }
  }

  // ---- combine the 4 groups within each wave (xor 16/32 share d-slice) ----
#pragma unroll
  for (int h = 0; h < 4; ++h) {
    float lh = lsum[h];
    lh += __shfl_xor(lh, 16, 64);
    lh += __shfl_xor(lh, 32, 64);
    lsum[h] = lh;
#pragma unroll
    for (int e = 0; e < 8; ++e) {
      float a = acc[h][e];
      a += __shfl_xor(a, 16, 64);
      a += __shfl_xor(a, 32, 64);
      acc[h][e] = a;
    }
  }
  if (grp == 0) {
#pragma unroll
    for (int h = 0; h < 4; ++h)
#pragma unroll
      for (int e = 0; e < 8; ++e) s_wacc[wvi][h][dbase + e] = acc[h][e];
    if (lig == 0) {
#pragma unroll
      for (int h = 0; h < 4; ++h) s_wl[wvi][h] = lsum[h];
    }
  }
  __syncthreads();
  // ---- combine the 4 waves, write partials ----
  for (int o = tid; o < NREP * HD; o += 256) {
    int h = o >> 7, d = o & (HD - 1);
    float sum = s_wacc[0][h][d] + s_wacc[1][h][d] + s_wacc[2][h][d] +
                s_wacc[3][h][d];
    partial_o[((size_t)(g * NREP + h) * RSPLIT + split) * HD + d] = sum;
  }
  if (tid < NREP) {
    int hg = g * NREP + tid;
    partial_m[hg * RSPLIT + split] = 0.f;
    partial_l[hg * RSPLIT + split] =
        s_wl[0][tid] + s_wl[1][tid] + s_wl[2][tid] + s_wl[3][tid];
  }
}

// ---------------------------------------------------------------------------
// Kernel 3: combine splits. One block (256 threads) per head.
// ---------------------------------------------------------------------------
__global__ __launch_bounds__(256) void combine_kernel(
    const float* __restrict__ partial_m, const float* __restrict__ partial_l,
    const float* __restrict__ partial_o, float* __restrict__ attn_out) {
  int h = blockIdx.x;
  int tid = threadIdx.x;
  __shared__ float s_m[RSPLIT], s_l[RSPLIT];
  __shared__ float s_acc[2][HD];
  if (tid < RSPLIT) {
    s_m[tid] = partial_m[h * RSPLIT + tid];
    s_l[tid] = partial_l[h * RSPLIT + tid];
  }
  __syncthreads();
  float M = -1e30f;
  for (int s = 0; s < RSPLIT; ++s) M = fmaxf(M, s_m[s]);
  float L = 0.f;
  for (int s = 0; s < RSPLIT; ++s) L += s_l[s] * __expf(s_m[s] - M);
  int d = tid & (HD - 1), half = tid >> 7;
  int hn = RSPLIT >> 1;
  float acc = 0.f;
#pragma unroll 4
  for (int s = half * hn; s < half * hn + hn; ++s)
    acc += __expf(s_m[s] - M) * partial_o[((size_t)h * RSPLIT + s) * HD + d];
  s_acc[half][d] = acc;
  __syncthreads();
  if (half == 0) attn_out[h * HD + d] = (s_acc[0][d] + s_acc[1][d]) / L;
}

// ---------------------------------------------------------------------------
// Kernel 4: out = attn @ wo.T
// ---------------------------------------------------------------------------
__global__ __launch_bounds__(256) void out_gemv_kernel(
    const float* __restrict__ attn, const float* __restrict__ wo,
    float* __restrict__ out) {
  int row = blockIdx.x * 4 + (threadIdx.x >> 6);
  int lane = threadIdx.x & 63;
  const float4* a4 = (const float4*)attn;
  const float4* w4 = (const float4*)(wo + (size_t)row * DIM);
  float a = 0.f;
#pragma unroll 4
  for (int c = lane; c < DIM / 4; c += 64) {
    float4 av = a4[c];
    float4 wv = w4[c];
    a += av.x * wv.x + av.y * wv.y + av.z * wv.z + av.w * wv.w;
  }
  for (int off = 32; off > 0; off >>= 1) a += __shfl_down(a, off, 64);
  if (lane == 0) out[row] = a;
}

extern "C" void kernel_launch(void* const* d_in, const int* in_sizes, int n_in,
                              void* d_out, int out_size, void* d_ws,
                              size_t ws_size, hipStream_t stream) {
  const float* x       = (const float*)d_in[0];
  const float* fc      = (const float*)d_in[1];
  const float* fs      = (const float*)d_in[2];
  const float* k_cache = (const float*)d_in[3];
  const float* v_cache = (const float*)d_in[4];
  const float* wq      = (const float*)d_in[5];
  const float* wk      = (const float*)d_in[6];
  const float* wv      = (const float*)d_in[7];
  const float* wo      = (const float*)d_in[8];
  float* out = (float*)d_out;

  int start_pos = in_sizes[3] / (NKV * HD);  // cache length
  int T = start_pos + 1;
  int CH = ((T + RSPLIT - 1) / RSPLIT + 15) & ~15;  // 256 for T=32768

  float* ws = (float*)d_ws;
  float* q_rope    = ws;                              // 4096
  float* k_new     = ws + 4096;                       // 1024
  float* v_new     = ws + 5120;                       // 1024
  float* attn_out  = ws + 6144;                       // 4096
  float* partial_m = ws + 10240;                      // NH*RSPLIT
  float* partial_l = partial_m + NH * RSPLIT;         // NH*RSPLIT
  float* partial_o = partial_l + NH * RSPLIT;         // NH*RSPLIT*HD

  qkv_rope_kernel<<<768, 256, 0, stream>>>(x, fc, fs, wq, wk, wv, q_rope,
                                           k_new, v_new);
  attn_partial_kernel<<<NKV * RSPLIT, 256, 0, stream>>>(
      q_rope, k_cache, v_cache, k_new, v_new, partial_m, partial_l, partial_o,
      start_pos, T, CH);
  combine_kernel<<<NH, 256, 0, stream>>>(partial_m, partial_l, partial_o,
                                         attn_out);
  out_gemv_kernel<<<1024, 256, 0, stream>>>(attn_out, wo, out);
}